// Round 18
// baseline (195.358 us; speedup 1.0000x reference)
//
#include <hip/hip_runtime.h>
#include <math.h>

#define DIM     1024
#define NHEAD   16
#define HD      64
#define BATCH   4
#define SEQ     2048
#define MTOT    (BATCH * SEQ)      // 8192
#define QKV_N   (3 * DIM)          // 3072

typedef __attribute__((ext_vector_type(8))) short bf16x8;
typedef __attribute__((ext_vector_type(4))) float f32x4;
typedef unsigned int u32;
typedef unsigned short u16;

__device__ __forceinline__ u16 f2bf(float f) {   // RNE fp32 -> bf16
    u32 u = __float_as_uint(f);
    return (u16)((u + 0x7fffu + ((u >> 16) & 1u)) >> 16);
}

__device__ __forceinline__ float exp2_fast(float x) {   // v_exp_f32 = 2^x
    float r; asm("v_exp_f32 %0, %1" : "=v"(r) : "v"(x)); return r;
}

__device__ __forceinline__ u32 cvtpk_bf16(float lo, float hi) {
    u32 r; asm("v_cvt_pk_bf16_f32 %0, %1, %2" : "=v"(r) : "v"(lo), "v"(hi));
    return r;
}

__device__ __forceinline__ void gload_lds16(const u16* g, u16* l) {
    // async global->LDS, 16B/lane; dest = wave-uniform base + lane*16
    __builtin_amdgcn_global_load_lds((const __attribute__((address_space(1))) u32*)g,
                                     (__attribute__((address_space(3))) u32*)l, 16, 0, 0);
}

// ---------------------------------------------------------------------------
// Prep (weights only now): blocks [0,768) transpose+cast w_qkv;
// [768,1024) transpose+cast w_proj. x-cast is fused into gemm_qkv.
// ---------------------------------------------------------------------------
__global__ __launch_bounds__(256) void prep(
    const float* __restrict__ wq, u16* __restrict__ wqt,
    const float* __restrict__ wp, u16* __restrict__ wpt)
{
    __shared__ float Ls[64][65];
    int i = blockIdx.x;
    const float* W; u16* Wt; int N;
    if (i < 768) { W = wq; Wt = wqt; N = QKV_N; }
    else         { i -= 768; W = wp; Wt = wpt; N = DIM; }
    const int k0 = (i & 15) * 64, n0 = (i >> 4) * 64;
    const int t = threadIdx.x;
    const int r = t >> 4, c4 = (t & 15) << 2;
    #pragma unroll
    for (int j = 0; j < 4; ++j) {
        const float4 v = *(const float4*)&W[(size_t)(k0 + r + j * 16) * N + n0 + c4];
        Ls[r + j * 16][c4 + 0] = v.x; Ls[r + j * 16][c4 + 1] = v.y;
        Ls[r + j * 16][c4 + 2] = v.z; Ls[r + j * 16][c4 + 3] = v.w;
    }
    __syncthreads();
    #pragma unroll
    for (int j = 0; j < 4; ++j) {
        const int nr = r + j * 16;
        ushort4 o;
        o.x = f2bf(Ls[c4 + 0][nr]); o.y = f2bf(Ls[c4 + 1][nr]);
        o.z = f2bf(Ls[c4 + 2][nr]); o.w = f2bf(Ls[c4 + 3][nr]);
        *(ushort4*)&Wt[(size_t)(n0 + nr) * DIM + k0 + c4] = o;
    }
}

// ===========================================================================
// bf16 MFMA GEMM mainloops. 128x128 tile, 4 waves, BK=32, source-swizzled
// LDS (slot ^= (row>>1)&3), 2-phase dbuf, 1 barrier/K-step.
//  - GEMM_MAINLOOP:      A bf16 via global_load_lds (used by gemm_proj)
//  - GEMM_MAINLOOP_F32A: A fp32 reg-staged + cvt_pk + ds_write (fused cast,
//    used by gemm_qkv; same slot involution as the gload path). B via gload.
// ===========================================================================
#define GEMM_STAGE_B(buf, kof, Bptr)                                           \
    _Pragma("unroll") for (int i = 0; i < 2; ++i) {                            \
        const int row = w * 32 + i * 16 + (lane >> 2);                         \
        const int slot = (lane & 3) ^ ((row >> 1) & 3);                        \
        gload_lds16(&Bptr[(size_t)(n0 + row) * DIM + (kof) + slot * 8],        \
                    &Bs[buf][(w * 32 + i * 16) * 32]);                         \
    }

#define GEMM_STAGE_A16(buf, kof, Aptr)                                         \
    _Pragma("unroll") for (int i = 0; i < 2; ++i) {                            \
        const int row = w * 32 + i * 16 + (lane >> 2);                         \
        const int slot = (lane & 3) ^ ((row >> 1) & 3);                        \
        gload_lds16(&Aptr[(size_t)(m0 + row) * DIM + (kof) + slot * 8],        \
                    &As[buf][(w * 32 + i * 16) * 32]);                         \
    }

#define GEMM_LOADA32(kof, Aptr)                                                \
    _Pragma("unroll") for (int i = 0; i < 2; ++i) {                            \
        const int row = w * 32 + i * 16 + (lane >> 2);                         \
        const int slot = (lane & 3) ^ ((row >> 1) & 3);                        \
        const float* ap = &Aptr[(size_t)(m0 + row) * DIM + (kof) + slot * 8];  \
        ra[i][0] = *(const float4*)ap;                                         \
        ra[i][1] = *(const float4*)(ap + 4);                                   \
    }

#define GEMM_WRITEA32(buf)                                                     \
    _Pragma("unroll") for (int i = 0; i < 2; ++i) {                            \
        const int row = w * 32 + i * 16 + (lane >> 2);                         \
        u32 pk4[4];                                                            \
        pk4[0] = cvtpk_bf16(ra[i][0].x, ra[i][0].y);                           \
        pk4[1] = cvtpk_bf16(ra[i][0].z, ra[i][0].w);                           \
        pk4[2] = cvtpk_bf16(ra[i][1].x, ra[i][1].y);                           \
        pk4[3] = cvtpk_bf16(ra[i][1].z, ra[i][1].w);                           \
        *(uint4*)&As[buf][row * 32 + (lane & 3) * 8] = *(uint4*)pk4;           \
    }

#define GEMM_PREAMBLE                                                          \
    const int t = threadIdx.x;                                                 \
    const int lane = t & 63, w = t >> 6;                                       \
    const int n0 = blockIdx.x * 128;                                           \
    const int m0 = blockIdx.y * 128;                                           \
    const int wm = (w & 1) * 64, wn = (w >> 1) * 64;                           \
    const int g = lane >> 4, li = lane & 15;                                   \
    f32x4 acc[4][4];                                                           \
    _Pragma("unroll") for (int mt = 0; mt < 4; ++mt)                           \
        _Pragma("unroll") for (int nt = 0; nt < 4; ++nt)                       \
            acc[mt][nt] = (f32x4){0.f, 0.f, 0.f, 0.f};

#define GEMM_COMPUTE(buf)                                                      \
    {                                                                          \
        bf16x8 a[4], b[4];                                                     \
        _Pragma("unroll") for (int mt = 0; mt < 4; ++mt) {                     \
            const int row = wm + mt * 16 + li;                                 \
            const int slot = g ^ ((row >> 1) & 3);                             \
            a[mt] = *(const bf16x8*)&As[buf][row * 32 + slot * 8];             \
        }                                                                      \
        _Pragma("unroll") for (int nt = 0; nt < 4; ++nt) {                     \
            const int row = wn + nt * 16 + li;                                 \
            const int slot = g ^ ((row >> 1) & 3);                             \
            b[nt] = *(const bf16x8*)&Bs[buf][row * 32 + slot * 8];             \
        }                                                                      \
        _Pragma("unroll") for (int mt = 0; mt < 4; ++mt)                       \
            _Pragma("unroll") for (int nt = 0; nt < 4; ++nt)                   \
                acc[mt][nt] = __builtin_amdgcn_mfma_f32_16x16x32_bf16(         \
                    a[mt], b[nt], acc[mt][nt], 0, 0, 0);                       \
    }

#define GEMM_MAINLOOP(Aptr, Bptr)                                              \
    __shared__ __align__(16) u16 As[2][128 * 32];                              \
    __shared__ __align__(16) u16 Bs[2][128 * 32];                              \
    GEMM_PREAMBLE                                                              \
    GEMM_STAGE_A16(0, 0, Aptr)                                                 \
    GEMM_STAGE_B(0, 0, Bptr)                                                   \
    __syncthreads();                                                           \
    int cur = 0;                                                               \
    for (int k0 = 0; k0 < DIM; k0 += 32) {                                     \
        if (k0 + 32 < DIM) {                                                   \
            GEMM_STAGE_A16(cur ^ 1, k0 + 32, Aptr)                             \
            GEMM_STAGE_B(cur ^ 1, k0 + 32, Bptr)                               \
        }                                                                      \
        GEMM_COMPUTE(cur)                                                      \
        __syncthreads();                                                       \
        cur ^= 1;                                                              \
    }

#define GEMM_MAINLOOP_F32A(Aptr, Bptr)                                         \
    __shared__ __align__(16) u16 As[2][128 * 32];                              \
    __shared__ __align__(16) u16 Bs[2][128 * 32];                              \
    GEMM_PREAMBLE                                                              \
    float4 ra[2][2];                                                           \
    GEMM_LOADA32(0, Aptr)                                                      \
    GEMM_STAGE_B(0, 0, Bptr)                                                   \
    GEMM_WRITEA32(0)                                                           \
    __syncthreads();                                                           \
    int cur = 0;                                                               \
    for (int k0 = 0; k0 < DIM; k0 += 32) {                                     \
        if (k0 + 32 < DIM) {                                                   \
            GEMM_LOADA32(k0 + 32, Aptr)                                        \
            GEMM_STAGE_B(cur ^ 1, k0 + 32, Bptr)                               \
        }                                                                      \
        GEMM_COMPUTE(cur)                                                      \
        if (k0 + 32 < DIM) { GEMM_WRITEA32(cur ^ 1) }                          \
        __syncthreads();                                                       \
        cur ^= 1;                                                              \
    }

// QKV GEMM (A = x fp32, fused cast): scatter to q/k/v bf16 [B,H,N,hd].
// Q pre-scaled by 0.125*log2(e) so attention softmax runs in exp2 domain.
#define QSCALE 0.18033688011112042f
__global__ __launch_bounds__(256) void gemm_qkv(
    const float* __restrict__ A, const u16* __restrict__ Bt,
    const float* __restrict__ bias,
    u16* __restrict__ qo, u16* __restrict__ ko, u16* __restrict__ vo)
{
    GEMM_MAINLOOP_F32A(A, Bt)
    #pragma unroll
    for (int nt = 0; nt < 4; ++nt) {
        const int n = n0 + wn + nt * 16 + li;
        const int which = n >> 10;               // 0=q 1=k 2=v
        const int head  = (n >> 6) & 15;
        const int hd    = n & 63;
        u16* dst = (which == 0) ? qo : (which == 1) ? ko : vo;
        const float scale = (which == 0) ? QSCALE : 1.0f;
        const float bv = bias[n];
        #pragma unroll
        for (int mt = 0; mt < 4; ++mt) {
            #pragma unroll
            for (int r = 0; r < 4; ++r) {
                const int m = m0 + wm + mt * 16 + g * 4 + r;
                const int bb = m >> 11, tok = m & 2047;
                dst[((size_t)(bb * NHEAD + head) * SEQ + tok) * HD + hd] =
                    f2bf((acc[mt][nt][r] + bv) * scale);
            }
        }
    }
}

// Projection GEMM: fp32 output + bias -> d_out.
__global__ __launch_bounds__(256) void gemm_proj(
    const u16* __restrict__ A, const u16* __restrict__ Bt,
    const float* __restrict__ bias, float* __restrict__ out)
{
    GEMM_MAINLOOP(A, Bt)
    #pragma unroll
    for (int nt = 0; nt < 4; ++nt) {
        const int n = n0 + wn + nt * 16 + li;
        const float bv = bias[n];
        #pragma unroll
        for (int mt = 0; mt < 4; ++mt) {
            #pragma unroll
            for (int r = 0; r < 4; ++r) {
                const int m = m0 + wm + mt * 16 + g * 4 + r;
                out[(size_t)m * DIM + n] = acc[mt][nt][r] + bv;
            }
        }
    }
}

// ===========================================================================
// MFMA flash attention (R17-proven 8-wave kernel + XCD-chunked swizzle).
// 512 thr, QBLK=256, zero-LDS P via kperm, fixed-m softmax, reg-staged
// 2-slot dbuf, one __syncthreads per tile, setprio on MFMA clusters.
// Swizzle: 512 blocks = 8 XCDs x 64; 64 consecutive flat-blocks (8 bh) per
// XCD -> per-XCD KV set 8 x 0.5 MB = 4 MB = one L2 (R11-proven mapping).
// ===========================================================================
#define LSTR 72
#define NKT  (SEQ / 64)
__global__ __launch_bounds__(512) void attn_mfma(
    const u16* __restrict__ q, const u16* __restrict__ k,
    const u16* __restrict__ v, u16* __restrict__ ao)
{
    __shared__ __align__(16) u16 Ks[2][64 * LSTR];
    __shared__ __align__(16) u16 Vt[2][64 * LSTR];

    const int t = threadIdx.x;
    const int lane = t & 63, w = t >> 6;        // w = 0..7
    const int g = lane >> 4, li = lane & 15;

    // XCD-chunked swizzle (512 blocks): xcd = flat&7 owns 64 consecutive swz
    int flat = blockIdx.y * 8 + blockIdx.x;     // gridDim.x = 8
    flat = (flat & 7) * 64 + (flat >> 3);
    const int q0 = (flat & 7) * 256;
    const int bh = flat >> 3;
    const size_t base = (size_t)bh * SEQ * HD;

    // Q B-frags, both halves: q-col = li, d-slice = ks*32 + g*8
    bf16x8 qf[2][2];
    #pragma unroll
    for (int h = 0; h < 2; ++h) {
        const size_t qrow = base + (size_t)(q0 + w * 32 + h * 16 + li) * HD;
        qf[h][0] = *(const bf16x8*)&q[qrow + g * 8];
        qf[h][1] = *(const bf16x8*)&q[qrow + 32 + g * 8];
    }

    float lsum[2] = {0.f, 0.f};
    f32x4 oacc[2][4];
    #pragma unroll
    for (int h = 0; h < 2; ++h)
        #pragma unroll
        for (int nt = 0; nt < 4; ++nt) oacc[h][nt] = (f32x4){0.f, 0.f, 0.f, 0.f};

    // ---- staging maps for 512 threads (in-bounds; coverage exact) ----
    const int kk = t >> 3;                     // LDS K row rho in [0,64)
    const int kh = (t & 7) << 3;               // hd chunk {0,8,...,56}
    const int kperm = (kk & 32) | (((kk >> 2) & 3) << 3)
                    | (((kk >> 4) & 1) << 2) | (kk & 3);   // global key for rho
    const int vkp = (t & 31) << 1;             // key pair {0,2,...,62}
    const int vh0 = (t >> 5) << 2;             // hd quad {0,4,...,60}

    // prefetch tile 0 into regs
    bf16x8 rk;
    ushort4 rv0, rv1;
    rk  = *(const bf16x8*)&k[base + (size_t)kperm * HD + kh];
    rv0 = *(const ushort4*)&v[base + (size_t)vkp * HD + vh0];
    rv1 = *(const ushort4*)&v[base + (size_t)(vkp + 1) * HD + vh0];
    {
        u16* Kn = Ks[0]; u16* Vn = Vt[0];
        *(bf16x8*)&Kn[kk * LSTR + kh] = rk;
        const u16 a0[4] = {rv0.x, rv0.y, rv0.z, rv0.w};
        const u16 b0[4] = {rv1.x, rv1.y, rv1.z, rv1.w};
        #pragma unroll
        for (int i = 0; i < 4; ++i)
            *(u32*)&Vn[(vh0 + i) * LSTR + vkp] = (u32)a0[i] | ((u32)b0[i] << 16);
    }
    __syncthreads();

    int cur = 0;
    for (int kt = 0; kt < NKT; ++kt) {
        const bool more = (kt + 1 < NKT);
        if (more) {   // issue next tile's global loads early (T14)
            const size_t kb = base + (size_t)(kt + 1) * 64 * HD;
            rk  = *(const bf16x8*)&k[kb + (size_t)kperm * HD + kh];
            rv0 = *(const ushort4*)&v[kb + (size_t)vkp * HD + vh0];
            rv1 = *(const ushort4*)&v[kb + (size_t)(vkp + 1) * HD + vh0];
        }
        const u16* Kc = Ks[cur];
        const u16* Vc = Vt[cur];

        // QK^T: s[h][nt][r] = S[key=kperm(16nt+4g+r)][q=li]
        f32x4 s[2][4];
        __builtin_amdgcn_s_setprio(1);
        #pragma unroll
        for (int nt = 0; nt < 4; ++nt) {
            const bf16x8 kf0 = *(const bf16x8*)&Kc[(nt * 16 + li) * LSTR + g * 8];
            const bf16x8 kf1 = *(const bf16x8*)&Kc[(nt * 16 + li) * LSTR + 32 + g * 8];
            #pragma unroll
            for (int h = 0; h < 2; ++h) {
                f32x4 c = (f32x4){0.f, 0.f, 0.f, 0.f};
                c = __builtin_amdgcn_mfma_f32_16x16x32_bf16(kf0, qf[h][0], c, 0, 0, 0);
                c = __builtin_amdgcn_mfma_f32_16x16x32_bf16(kf1, qf[h][1], c, 0, 0, 0);
                s[h][nt] = c;
            }
        }
        __builtin_amdgcn_s_setprio(0);

        // fixed-m softmax + in-register P pack (kperm makes pb = own regs)
        bf16x8 pb[2][2];
        #pragma unroll
        for (int h = 0; h < 2; ++h) {
            float rs = 0.f;
            #pragma unroll
            for (int nt = 0; nt < 4; ++nt)
                #pragma unroll
                for (int r = 0; r < 4; ++r) {
                    const float p = exp2_fast(s[h][nt][r]);
                    s[h][nt][r] = p;
                    rs += p;
                }
            lsum[h] += rs;
            #pragma unroll
            for (int ks = 0; ks < 2; ++ks) {
                union { u32 u[4]; bf16x8 v8; } uu;
                uu.u[0] = cvtpk_bf16(s[h][2 * ks][0],     s[h][2 * ks][1]);
                uu.u[1] = cvtpk_bf16(s[h][2 * ks][2],     s[h][2 * ks][3]);
                uu.u[2] = cvtpk_bf16(s[h][2 * ks + 1][0], s[h][2 * ks + 1][1]);
                uu.u[3] = cvtpk_bf16(s[h][2 * ks + 1][2], s[h][2 * ks + 1][3]);
                pb[h][ks] = uu.v8;
            }
        }

        // PV: O^T[hd][q] += V^T[hd][key] * P^T[key][q]
        __builtin_amdgcn_s_setprio(1);
        #pragma unroll
        for (int ks = 0; ks < 2; ++ks) {
            #pragma unroll
            for (int nt = 0; nt < 4; ++nt) {
                const bf16x8 vb = *(const bf16x8*)&Vc[(nt * 16 + li) * LSTR + ks * 32 + g * 8];
                #pragma unroll
                for (int h = 0; h < 2; ++h)
                    oacc[h][nt] = __builtin_amdgcn_mfma_f32_16x16x32_bf16(
                        vb, pb[h][ks], oacc[h][nt], 0, 0, 0);
            }
        }
        __builtin_amdgcn_s_setprio(0);

        // stage next tile into the other buffer (loads had compute to land)
        if (more) {
            u16* Kn = Ks[cur ^ 1]; u16* Vn = Vt[cur ^ 1];
            *(bf16x8*)&Kn[kk * LSTR + kh] = rk;
            const u16 a0[4] = {rv0.x, rv0.y, rv0.z, rv0.w};
            const u16 b0[4] = {rv1.x, rv1.y, rv1.z, rv1.w};
            #pragma unroll
            for (int i = 0; i < 4; ++i)
                *(u32*)&Vn[(vh0 + i) * LSTR + vkp] = (u32)a0[i] | ((u32)b0[i] << 16);
        }
        __syncthreads();
        cur ^= 1;
    }

    // epilogue: reduce l over g-groups (each lane owns q=li), normalize, store
    const int bb = bh >> 4, hh = bh & 15;
    #pragma unroll
    for (int h = 0; h < 2; ++h) {
        float lf = lsum[h];
        lf += __shfl_xor(lf, 16);
        lf += __shfl_xor(lf, 32);
        const float inv = 1.0f / lf;
        const int tok = q0 + w * 32 + h * 16 + li;
        u16* dst = &ao[(size_t)(bb * SEQ + tok) * DIM + hh * HD];
        #pragma unroll
        for (int nt = 0; nt < 4; ++nt) {
            const u32 p0 = cvtpk_bf16(oacc[h][nt][0] * inv, oacc[h][nt][1] * inv);
            const u32 p1 = cvtpk_bf16(oacc[h][nt][2] * inv, oacc[h][nt][3] * inv);
            *(u32*)&dst[nt * 16 + g * 4]     = p0;
            *(u32*)&dst[nt * 16 + g * 4 + 2] = p1;
        }
    }
}

extern "C" void kernel_launch(void* const* d_in, const int* in_sizes, int n_in,
                              void* d_out, int out_size, void* d_ws, size_t ws_size,
                              hipStream_t stream)
{
    const float* x      = (const float*)d_in[0];
    const float* w_qkv  = (const float*)d_in[1];
    const float* b_qkv  = (const float*)d_in[2];
    const float* w_proj = (const float*)d_in[3];
    const float* b_proj = (const float*)d_in[4];
    float* out = (float*)d_out;

    // bf16 workspace (~76 MB; xb slot retained but unused)
    u16* xb  = (u16*)d_ws;                         // (unused; layout kept)
    u16* wqt = xb  + (size_t)MTOT * DIM;           // 3072x1024 (transposed)
    u16* wpt = wqt + (size_t)QKV_N * DIM;          // 1024x1024 (transposed)
    u16* qb  = wpt + (size_t)DIM * DIM;            // [B,H,N,hd]
    u16* kb  = qb  + (size_t)MTOT * DIM;
    u16* vb  = kb  + (size_t)MTOT * DIM;           // [B,H,N,hd]
    u16* aob = vb  + (size_t)MTOT * DIM;           // [B,N,D]

    prep<<<1024, 256, 0, stream>>>(w_qkv, wqt, w_proj, wpt);
    gemm_qkv<<<dim3(QKV_N / 128, MTOT / 128), 256, 0, stream>>>(x, wqt, b_qkv, qb, kb, vb);
    attn_mfma<<<dim3(SEQ / 256, BATCH * NHEAD), 512, 0, stream>>>(qb, kb, vb, aob);
    gemm_proj<<<dim3(DIM / 128, MTOT / 128), 256, 0, stream>>>(aob, wpt, b_proj, out);
}

// Round 19
// 192.775 us; speedup vs baseline: 1.0134x; 1.0134x over previous
//
#include <hip/hip_runtime.h>
#include <math.h>

#define DIM     1024
#define NHEAD   16
#define HD      64
#define BATCH   4
#define SEQ     2048
#define MTOT    (BATCH * SEQ)      // 8192
#define QKV_N   (3 * DIM)          // 3072

typedef __attribute__((ext_vector_type(8))) short bf16x8;
typedef __attribute__((ext_vector_type(4))) float f32x4;
typedef unsigned int u32;
typedef unsigned short u16;

__device__ __forceinline__ u16 f2bf(float f) {   // RNE fp32 -> bf16
    u32 u = __float_as_uint(f);
    return (u16)((u + 0x7fffu + ((u >> 16) & 1u)) >> 16);
}

__device__ __forceinline__ float exp2_fast(float x) {   // v_exp_f32 = 2^x
    float r; asm("v_exp_f32 %0, %1" : "=v"(r) : "v"(x)); return r;
}

__device__ __forceinline__ u32 cvtpk_bf16(float lo, float hi) {
    u32 r; asm("v_cvt_pk_bf16_f32 %0, %1, %2" : "=v"(r) : "v"(lo), "v"(hi));
    return r;
}

__device__ __forceinline__ void gload_lds16(const u16* g, u16* l) {
    // async global->LDS, 16B/lane; dest = wave-uniform base + lane*16
    __builtin_amdgcn_global_load_lds((const __attribute__((address_space(1))) u32*)g,
                                     (__attribute__((address_space(3))) u32*)l, 16, 0, 0);
}

// ---------------------------------------------------------------------------
// Fused prep (single launch): blocks [0,8192) cast x fp32->bf16;
// [8192,8960) transpose+cast w_qkv; [8960,9216) transpose+cast w_proj.
// ---------------------------------------------------------------------------
__global__ __launch_bounds__(256) void prep(
    const float* __restrict__ x,  u16* __restrict__ xb,
    const float* __restrict__ wq, u16* __restrict__ wqt,
    const float* __restrict__ wp, u16* __restrict__ wpt)
{
    const int b = blockIdx.x;
    if (b < 8192) {   // cast x: 1024 f32 per block
        const int i = (b * 256 + threadIdx.x) * 4;
        const float4 v = *(const float4*)&x[i];
        ushort4 o;
        o.x = f2bf(v.x); o.y = f2bf(v.y); o.z = f2bf(v.z); o.w = f2bf(v.w);
        *(ushort4*)&xb[i] = o;
        return;
    }
    __shared__ float Ls[64][65];
    int i = b - 8192;
    const float* W; u16* Wt; int N;
    if (i < 768) { W = wq; Wt = wqt; N = QKV_N; }
    else         { i -= 768; W = wp; Wt = wpt; N = DIM; }
    const int k0 = (i & 15) * 64, n0 = (i >> 4) * 64;
    const int t = threadIdx.x;
    const int r = t >> 4, c4 = (t & 15) << 2;
    #pragma unroll
    for (int j = 0; j < 4; ++j) {
        const float4 v = *(const float4*)&W[(size_t)(k0 + r + j * 16) * N + n0 + c4];
        Ls[r + j * 16][c4 + 0] = v.x; Ls[r + j * 16][c4 + 1] = v.y;
        Ls[r + j * 16][c4 + 2] = v.z; Ls[r + j * 16][c4 + 3] = v.w;
    }
    __syncthreads();
    #pragma unroll
    for (int j = 0; j < 4; ++j) {
        const int nr = r + j * 16;
        ushort4 o;
        o.x = f2bf(Ls[c4 + 0][nr]); o.y = f2bf(Ls[c4 + 1][nr]);
        o.z = f2bf(Ls[c4 + 2][nr]); o.w = f2bf(Ls[c4 + 3][nr]);
        *(ushort4*)&Wt[(size_t)(n0 + nr) * DIM + k0 + c4] = o;
    }
}

// ===========================================================================
// bf16 MFMA GEMM, C[M][N] = A[M][K] * Bt[N][K]^T.  K = 1024.
// 128x128 tile, 4 waves (64x64 each, 4x4 frags), BK=32, global_load_lds w=16,
// source-swizzled LDS (slot ^= (row>>1)&3). 2-phase dbuf, 1 barrier/K-step.
// ===========================================================================
#define GEMM_STAGE(buf, kof, Aptr, Bptr)                                       \
    _Pragma("unroll") for (int i = 0; i < 2; ++i) {                            \
        const int row = w * 32 + i * 16 + (lane >> 2);                         \
        const int slot = (lane & 3) ^ ((row >> 1) & 3);                        \
        gload_lds16(&Aptr[(size_t)(m0 + row) * DIM + (kof) + slot * 8],        \
                    &As[buf][(w * 32 + i * 16) * 32]);                         \
        gload_lds16(&Bptr[(size_t)(n0 + row) * DIM + (kof) + slot * 8],        \
                    &Bs[buf][(w * 32 + i * 16) * 32]);                         \
    }

#define GEMM_MAINLOOP(Aptr, Bptr)                                              \
    __shared__ __align__(16) u16 As[2][128 * 32];                              \
    __shared__ __align__(16) u16 Bs[2][128 * 32];                              \
    const int t = threadIdx.x;                                                 \
    const int lane = t & 63, w = t >> 6;                                       \
    const int n0 = blockIdx.x * 128;                                           \
    const int m0 = blockIdx.y * 128;                                           \
    const int wm = (w & 1) * 64, wn = (w >> 1) * 64;                           \
    const int g = lane >> 4, li = lane & 15;                                   \
    f32x4 acc[4][4];                                                           \
    _Pragma("unroll") for (int mt = 0; mt < 4; ++mt)                           \
        _Pragma("unroll") for (int nt = 0; nt < 4; ++nt)                       \
            acc[mt][nt] = (f32x4){0.f, 0.f, 0.f, 0.f};                         \
    GEMM_STAGE(0, 0, Aptr, Bptr)                                               \
    __syncthreads();                                                           \
    int cur = 0;                                                               \
    for (int k0 = 0; k0 < DIM; k0 += 32) {                                     \
        if (k0 + 32 < DIM) { GEMM_STAGE(cur ^ 1, k0 + 32, Aptr, Bptr) }        \
        bf16x8 a[4], b[4];                                                     \
        _Pragma("unroll") for (int mt = 0; mt < 4; ++mt) {                     \
            const int row = wm + mt * 16 + li;                                 \
            const int slot = g ^ ((row >> 1) & 3);                             \
            a[mt] = *(const bf16x8*)&As[cur][row * 32 + slot * 8];             \
        }                                                                      \
        _Pragma("unroll") for (int nt = 0; nt < 4; ++nt) {                     \
            const int row = wn + nt * 16 + li;                                 \
            const int slot = g ^ ((row >> 1) & 3);                             \
            b[nt] = *(const bf16x8*)&Bs[cur][row * 32 + slot * 8];             \
        }                                                                      \
        _Pragma("unroll") for (int mt = 0; mt < 4; ++mt)                       \
            _Pragma("unroll") for (int nt = 0; nt < 4; ++nt)                   \
                acc[mt][nt] = __builtin_amdgcn_mfma_f32_16x16x32_bf16(         \
                    a[mt], b[nt], acc[mt][nt], 0, 0, 0);                       \
        __syncthreads();                                                       \
        cur ^= 1;                                                              \
    }

// QKV GEMM: scatter to q/k/v bf16 [B,H,N,hd].
// Q pre-scaled by 0.125*log2(e) so attention softmax runs in exp2 domain.
#define QSCALE 0.18033688011112042f
__global__ __launch_bounds__(256) void gemm_qkv(
    const u16* __restrict__ A, const u16* __restrict__ Bt,
    const float* __restrict__ bias,
    u16* __restrict__ qo, u16* __restrict__ ko, u16* __restrict__ vo)
{
    GEMM_MAINLOOP(A, Bt)
    #pragma unroll
    for (int nt = 0; nt < 4; ++nt) {
        const int n = n0 + wn + nt * 16 + li;
        const int which = n >> 10;               // 0=q 1=k 2=v
        const int head  = (n >> 6) & 15;
        const int hd    = n & 63;
        u16* dst = (which == 0) ? qo : (which == 1) ? ko : vo;
        const float scale = (which == 0) ? QSCALE : 1.0f;
        const float bv = bias[n];
        #pragma unroll
        for (int mt = 0; mt < 4; ++mt) {
            #pragma unroll
            for (int r = 0; r < 4; ++r) {
                const int m = m0 + wm + mt * 16 + g * 4 + r;
                const int bb = m >> 11, tok = m & 2047;
                dst[((size_t)(bb * NHEAD + head) * SEQ + tok) * HD + hd] =
                    f2bf((acc[mt][nt][r] + bv) * scale);
            }
        }
    }
}

// Projection GEMM: fp32 output + bias -> d_out.
__global__ __launch_bounds__(256) void gemm_proj(
    const u16* __restrict__ A, const u16* __restrict__ Bt,
    const float* __restrict__ bias, float* __restrict__ out)
{
    GEMM_MAINLOOP(A, Bt)
    #pragma unroll
    for (int nt = 0; nt < 4; ++nt) {
        const int n = n0 + wn + nt * 16 + li;
        const float bv = bias[n];
        #pragma unroll
        for (int mt = 0; mt < 4; ++mt) {
            #pragma unroll
            for (int r = 0; r < 4; ++r) {
                const int m = m0 + wm + mt * 16 + g * 4 + r;
                out[(size_t)m * DIM + n] = acc[mt][nt][r] + bv;
            }
        }
    }
}

// ===========================================================================
// MFMA flash attention (R17 8-wave kernel + R18-proven XCD-chunked swizzle).
// 512 thr, QBLK=256, zero-LDS P via kperm, fixed-m softmax, reg-staged
// 2-slot dbuf, one __syncthreads per tile, setprio on MFMA clusters.
// Swizzle: 512 blocks = 8 XCDs x 64; 64 consecutive flat-blocks (8 bh) per
// XCD -> per-XCD KV set 4 MB = one L2 (FETCH 139 -> 24.6 MB measured).
// ===========================================================================
#define LSTR 72
#define NKT  (SEQ / 64)
__global__ __launch_bounds__(512) void attn_mfma(
    const u16* __restrict__ q, const u16* __restrict__ k,
    const u16* __restrict__ v, u16* __restrict__ ao)
{
    __shared__ __align__(16) u16 Ks[2][64 * LSTR];
    __shared__ __align__(16) u16 Vt[2][64 * LSTR];

    const int t = threadIdx.x;
    const int lane = t & 63, w = t >> 6;        // w = 0..7
    const int g = lane >> 4, li = lane & 15;

    // XCD-chunked swizzle (512 blocks): xcd = flat&7 owns 64 consecutive swz
    int flat = blockIdx.y * 8 + blockIdx.x;     // gridDim.x = 8
    flat = (flat & 7) * 64 + (flat >> 3);
    const int q0 = (flat & 7) * 256;
    const int bh = flat >> 3;
    const size_t base = (size_t)bh * SEQ * HD;

    // Q B-frags, both halves: q-col = li, d-slice = ks*32 + g*8
    bf16x8 qf[2][2];
    #pragma unroll
    for (int h = 0; h < 2; ++h) {
        const size_t qrow = base + (size_t)(q0 + w * 32 + h * 16 + li) * HD;
        qf[h][0] = *(const bf16x8*)&q[qrow + g * 8];
        qf[h][1] = *(const bf16x8*)&q[qrow + 32 + g * 8];
    }

    float lsum[2] = {0.f, 0.f};
    f32x4 oacc[2][4];
    #pragma unroll
    for (int h = 0; h < 2; ++h)
        #pragma unroll
        for (int nt = 0; nt < 4; ++nt) oacc[h][nt] = (f32x4){0.f, 0.f, 0.f, 0.f};

    // ---- staging maps for 512 threads (in-bounds; coverage exact) ----
    const int kk = t >> 3;                     // LDS K row rho in [0,64)
    const int kh = (t & 7) << 3;               // hd chunk {0,8,...,56}
    const int kperm = (kk & 32) | (((kk >> 2) & 3) << 3)
                    | (((kk >> 4) & 1) << 2) | (kk & 3);   // global key for rho
    const int vkp = (t & 31) << 1;             // key pair {0,2,...,62}
    const int vh0 = (t >> 5) << 2;             // hd quad {0,4,...,60}

    // prefetch tile 0 into regs
    bf16x8 rk;
    ushort4 rv0, rv1;
    rk  = *(const bf16x8*)&k[base + (size_t)kperm * HD + kh];
    rv0 = *(const ushort4*)&v[base + (size_t)vkp * HD + vh0];
    rv1 = *(const ushort4*)&v[base + (size_t)(vkp + 1) * HD + vh0];
    {
        u16* Kn = Ks[0]; u16* Vn = Vt[0];
        *(bf16x8*)&Kn[kk * LSTR + kh] = rk;
        const u16 a0[4] = {rv0.x, rv0.y, rv0.z, rv0.w};
        const u16 b0[4] = {rv1.x, rv1.y, rv1.z, rv1.w};
        #pragma unroll
        for (int i = 0; i < 4; ++i)
            *(u32*)&Vn[(vh0 + i) * LSTR + vkp] = (u32)a0[i] | ((u32)b0[i] << 16);
    }
    __syncthreads();

    int cur = 0;
    for (int kt = 0; kt < NKT; ++kt) {
        const bool more = (kt + 1 < NKT);
        if (more) {   // issue next tile's global loads early (T14)
            const size_t kb = base + (size_t)(kt + 1) * 64 * HD;
            rk  = *(const bf16x8*)&k[kb + (size_t)kperm * HD + kh];
            rv0 = *(const ushort4*)&v[kb + (size_t)vkp * HD + vh0];
            rv1 = *(const ushort4*)&v[kb + (size_t)(vkp + 1) * HD + vh0];
        }
        const u16* Kc = Ks[cur];
        const u16* Vc = Vt[cur];

        // QK^T: s[h][nt][r] = S[key=kperm(16nt+4g+r)][q=li]
        f32x4 s[2][4];
        __builtin_amdgcn_s_setprio(1);
        #pragma unroll
        for (int nt = 0; nt < 4; ++nt) {
            const bf16x8 kf0 = *(const bf16x8*)&Kc[(nt * 16 + li) * LSTR + g * 8];
            const bf16x8 kf1 = *(const bf16x8*)&Kc[(nt * 16 + li) * LSTR + 32 + g * 8];
            #pragma unroll
            for (int h = 0; h < 2; ++h) {
                f32x4 c = (f32x4){0.f, 0.f, 0.f, 0.f};
                c = __builtin_amdgcn_mfma_f32_16x16x32_bf16(kf0, qf[h][0], c, 0, 0, 0);
                c = __builtin_amdgcn_mfma_f32_16x16x32_bf16(kf1, qf[h][1], c, 0, 0, 0);
                s[h][nt] = c;
            }
        }
        __builtin_amdgcn_s_setprio(0);

        // fixed-m softmax + in-register P pack (kperm makes pb = own regs)
        bf16x8 pb[2][2];
        #pragma unroll
        for (int h = 0; h < 2; ++h) {
            float rs = 0.f;
            #pragma unroll
            for (int nt = 0; nt < 4; ++nt)
                #pragma unroll
                for (int r = 0; r < 4; ++r) {
                    const float p = exp2_fast(s[h][nt][r]);
                    s[h][nt][r] = p;
                    rs += p;
                }
            lsum[h] += rs;
            #pragma unroll
            for (int ks = 0; ks < 2; ++ks) {
                union { u32 u[4]; bf16x8 v8; } uu;
                uu.u[0] = cvtpk_bf16(s[h][2 * ks][0],     s[h][2 * ks][1]);
                uu.u[1] = cvtpk_bf16(s[h][2 * ks][2],     s[h][2 * ks][3]);
                uu.u[2] = cvtpk_bf16(s[h][2 * ks + 1][0], s[h][2 * ks + 1][1]);
                uu.u[3] = cvtpk_bf16(s[h][2 * ks + 1][2], s[h][2 * ks + 1][3]);
                pb[h][ks] = uu.v8;
            }
        }

        // PV: O^T[hd][q] += V^T[hd][key] * P^T[key][q]
        __builtin_amdgcn_s_setprio(1);
        #pragma unroll
        for (int ks = 0; ks < 2; ++ks) {
            #pragma unroll
            for (int nt = 0; nt < 4; ++nt) {
                const bf16x8 vb = *(const bf16x8*)&Vc[(nt * 16 + li) * LSTR + ks * 32 + g * 8];
                #pragma unroll
                for (int h = 0; h < 2; ++h)
                    oacc[h][nt] = __builtin_amdgcn_mfma_f32_16x16x32_bf16(
                        vb, pb[h][ks], oacc[h][nt], 0, 0, 0);
            }
        }
        __builtin_amdgcn_s_setprio(0);

        // stage next tile into the other buffer (loads had compute to land)
        if (more) {
            u16* Kn = Ks[cur ^ 1]; u16* Vn = Vt[cur ^ 1];
            *(bf16x8*)&Kn[kk * LSTR + kh] = rk;
            const u16 a0[4] = {rv0.x, rv0.y, rv0.z, rv0.w};
            const u16 b0[4] = {rv1.x, rv1.y, rv1.z, rv1.w};
            #pragma unroll
            for (int i = 0; i < 4; ++i)
                *(u32*)&Vn[(vh0 + i) * LSTR + vkp] = (u32)a0[i] | ((u32)b0[i] << 16);
        }
        __syncthreads();
        cur ^= 1;
    }

    // epilogue: reduce l over g-groups (each lane owns q=li), normalize, store
    const int bb = bh >> 4, hh = bh & 15;
    #pragma unroll
    for (int h = 0; h < 2; ++h) {
        float lf = lsum[h];
        lf += __shfl_xor(lf, 16);
        lf += __shfl_xor(lf, 32);
        const float inv = 1.0f / lf;
        const int tok = q0 + w * 32 + h * 16 + li;
        u16* dst = &ao[(size_t)(bb * SEQ + tok) * DIM + hh * HD];
        #pragma unroll
        for (int nt = 0; nt < 4; ++nt) {
            const u32 p0 = cvtpk_bf16(oacc[h][nt][0] * inv, oacc[h][nt][1] * inv);
            const u32 p1 = cvtpk_bf16(oacc[h][nt][2] * inv, oacc[h][nt][3] * inv);
            *(u32*)&dst[nt * 16 + g * 4]     = p0;
            *(u32*)&dst[nt * 16 + g * 4 + 2] = p1;
        }
    }
}

extern "C" void kernel_launch(void* const* d_in, const int* in_sizes, int n_in,
                              void* d_out, int out_size, void* d_ws, size_t ws_size,
                              hipStream_t stream)
{
    const float* x      = (const float*)d_in[0];
    const float* w_qkv  = (const float*)d_in[1];
    const float* b_qkv  = (const float*)d_in[2];
    const float* w_proj = (const float*)d_in[3];
    const float* b_proj = (const float*)d_in[4];
    float* out = (float*)d_out;

    // bf16 workspace (~92 MB)
    u16* xb  = (u16*)d_ws;                         // 8192x1024
    u16* wqt = xb  + (size_t)MTOT * DIM;           // 3072x1024 (transposed)
    u16* wpt = wqt + (size_t)QKV_N * DIM;          // 1024x1024 (transposed)
    u16* qb  = wpt + (size_t)DIM * DIM;            // [B,H,N,hd]
    u16* kb  = qb  + (size_t)MTOT * DIM;
    u16* vb  = kb  + (size_t)MTOT * DIM;           // [B,H,N,hd]
    u16* aob = vb  + (size_t)MTOT * DIM;           // [B,N,D]

    prep<<<8192 + 768 + 256, 256, 0, stream>>>(x, xb, w_qkv, wqt, w_proj, wpt);
    gemm_qkv<<<dim3(QKV_N / 128, MTOT / 128), 256, 0, stream>>>(xb, wqt, b_qkv, qb, kb, vb);
    attn_mfma<<<dim3(SEQ / 256, BATCH * NHEAD), 512, 0, stream>>>(qb, kb, vb, aob);
    gemm_proj<<<dim3(DIM / 128, MTOT / 128), 256, 0, stream>>>(aob, wpt, b_proj, out);
}

// Round 20
// 188.743 us; speedup vs baseline: 1.0350x; 1.0214x over previous
//
#include <hip/hip_runtime.h>
#include <math.h>

#define DIM     1024
#define NHEAD   16
#define HD      64
#define BATCH   4
#define SEQ     2048
#define MTOT    (BATCH * SEQ)      // 8192
#define QKV_N   (3 * DIM)          // 3072

typedef __attribute__((ext_vector_type(8))) short bf16x8;
typedef __attribute__((ext_vector_type(4))) float f32x4;
typedef unsigned int u32;
typedef unsigned short u16;

__device__ __forceinline__ u16 f2bf(float f) {   // RNE fp32 -> bf16
    u32 u = __float_as_uint(f);
    return (u16)((u + 0x7fffu + ((u >> 16) & 1u)) >> 16);
}

__device__ __forceinline__ float exp2_fast(float x) {   // v_exp_f32 = 2^x
    float r; asm("v_exp_f32 %0, %1" : "=v"(r) : "v"(x)); return r;
}

__device__ __forceinline__ u32 cvtpk_bf16(float lo, float hi) {
    u32 r; asm("v_cvt_pk_bf16_f32 %0, %1, %2" : "=v"(r) : "v"(lo), "v"(hi));
    return r;
}

__device__ __forceinline__ void gload_lds16(const u16* g, u16* l) {
    // async global->LDS, 16B/lane; dest = wave-uniform base + lane*16
    __builtin_amdgcn_global_load_lds((const __attribute__((address_space(1))) u32*)g,
                                     (__attribute__((address_space(3))) u32*)l, 16, 0, 0);
}

// ---------------------------------------------------------------------------
// Fused prep (single launch): blocks [0,8192) cast x fp32->bf16;
// [8192,8960) transpose+cast w_qkv; [8960,9216) transpose+cast w_proj.
// ---------------------------------------------------------------------------
__global__ __launch_bounds__(256) void prep(
    const float* __restrict__ x,  u16* __restrict__ xb,
    const float* __restrict__ wq, u16* __restrict__ wqt,
    const float* __restrict__ wp, u16* __restrict__ wpt)
{
    const int b = blockIdx.x;
    if (b < 8192) {   // cast x: 1024 f32 per block
        const int i = (b * 256 + threadIdx.x) * 4;
        const float4 v = *(const float4*)&x[i];
        ushort4 o;
        o.x = f2bf(v.x); o.y = f2bf(v.y); o.z = f2bf(v.z); o.w = f2bf(v.w);
        *(ushort4*)&xb[i] = o;
        return;
    }
    __shared__ float Ls[64][65];
    int i = b - 8192;
    const float* W; u16* Wt; int N;
    if (i < 768) { W = wq; Wt = wqt; N = QKV_N; }
    else         { i -= 768; W = wp; Wt = wpt; N = DIM; }
    const int k0 = (i & 15) * 64, n0 = (i >> 4) * 64;
    const int t = threadIdx.x;
    const int r = t >> 4, c4 = (t & 15) << 2;
    #pragma unroll
    for (int j = 0; j < 4; ++j) {
        const float4 v = *(const float4*)&W[(size_t)(k0 + r + j * 16) * N + n0 + c4];
        Ls[r + j * 16][c4 + 0] = v.x; Ls[r + j * 16][c4 + 1] = v.y;
        Ls[r + j * 16][c4 + 2] = v.z; Ls[r + j * 16][c4 + 3] = v.w;
    }
    __syncthreads();
    #pragma unroll
    for (int j = 0; j < 4; ++j) {
        const int nr = r + j * 16;
        ushort4 o;
        o.x = f2bf(Ls[c4 + 0][nr]); o.y = f2bf(Ls[c4 + 1][nr]);
        o.z = f2bf(Ls[c4 + 2][nr]); o.w = f2bf(Ls[c4 + 3][nr]);
        *(ushort4*)&Wt[(size_t)(n0 + nr) * DIM + k0 + c4] = o;
    }
}

// ===========================================================================
// bf16 MFMA GEMM, C[M][N] = A[M][K] * Bt[N][K]^T.  K = 1024.
// 128x128 tile, 4 waves (64x64 each, 4x4 frags), BK=32, global_load_lds w=16,
// source-swizzled LDS (slot ^= (row>>1)&3). 2-phase dbuf, 1 barrier/K-step.
// ===========================================================================
#define GEMM_STAGE(buf, kof, Aptr, Bptr)                                       \
    _Pragma("unroll") for (int i = 0; i < 2; ++i) {                            \
        const int row = w * 32 + i * 16 + (lane >> 2);                         \
        const int slot = (lane & 3) ^ ((row >> 1) & 3);                        \
        gload_lds16(&Aptr[(size_t)(m0 + row) * DIM + (kof) + slot * 8],        \
                    &As[buf][(w * 32 + i * 16) * 32]);                         \
        gload_lds16(&Bptr[(size_t)(n0 + row) * DIM + (kof) + slot * 8],        \
                    &Bs[buf][(w * 32 + i * 16) * 32]);                         \
    }

#define GEMM_MAINLOOP(Aptr, Bptr)                                              \
    __shared__ __align__(16) u16 As[2][128 * 32];                              \
    __shared__ __align__(16) u16 Bs[2][128 * 32];                              \
    const int t = threadIdx.x;                                                 \
    const int lane = t & 63, w = t >> 6;                                       \
    const int n0 = blockIdx.x * 128;                                           \
    const int m0 = blockIdx.y * 128;                                           \
    const int wm = (w & 1) * 64, wn = (w >> 1) * 64;                           \
    const int g = lane >> 4, li = lane & 15;                                   \
    f32x4 acc[4][4];                                                           \
    _Pragma("unroll") for (int mt = 0; mt < 4; ++mt)                           \
        _Pragma("unroll") for (int nt = 0; nt < 4; ++nt)                       \
            acc[mt][nt] = (f32x4){0.f, 0.f, 0.f, 0.f};                         \
    GEMM_STAGE(0, 0, Aptr, Bptr)                                               \
    __syncthreads();                                                           \
    int cur = 0;                                                               \
    for (int k0 = 0; k0 < DIM; k0 += 32) {                                     \
        if (k0 + 32 < DIM) { GEMM_STAGE(cur ^ 1, k0 + 32, Aptr, Bptr) }        \
        bf16x8 a[4], b[4];                                                     \
        _Pragma("unroll") for (int mt = 0; mt < 4; ++mt) {                     \
            const int row = wm + mt * 16 + li;                                 \
            const int slot = g ^ ((row >> 1) & 3);                             \
            a[mt] = *(const bf16x8*)&As[cur][row * 32 + slot * 8];             \
        }                                                                      \
        _Pragma("unroll") for (int nt = 0; nt < 4; ++nt) {                     \
            const int row = wn + nt * 16 + li;                                 \
            const int slot = g ^ ((row >> 1) & 3);                             \
            b[nt] = *(const bf16x8*)&Bs[cur][row * 32 + slot * 8];             \
        }                                                                      \
        _Pragma("unroll") for (int mt = 0; mt < 4; ++mt)                       \
            _Pragma("unroll") for (int nt = 0; nt < 4; ++nt)                   \
                acc[mt][nt] = __builtin_amdgcn_mfma_f32_16x16x32_bf16(         \
                    a[mt], b[nt], acc[mt][nt], 0, 0, 0);                       \
        __syncthreads();                                                       \
        cur ^= 1;                                                              \
    }

// QKV GEMM: scatter to q/k bf16 [B,H,N,hd]; V stored TRANSPOSED [B,H,hd,SEQ]
// (R18-proven epilogue; enables linear global_load_lds V staging in attn).
// Q pre-scaled by 0.125*log2(e) so attention softmax runs in exp2 domain.
#define QSCALE 0.18033688011112042f
__global__ __launch_bounds__(256) void gemm_qkv(
    const u16* __restrict__ A, const u16* __restrict__ Bt,
    const float* __restrict__ bias,
    u16* __restrict__ qo, u16* __restrict__ ko, u16* __restrict__ vo)
{
    GEMM_MAINLOOP(A, Bt)
    #pragma unroll
    for (int nt = 0; nt < 4; ++nt) {
        const int n = n0 + wn + nt * 16 + li;
        const int which = n >> 10;               // 0=q 1=k 2=v (uniform per nt)
        const int head  = (n >> 6) & 15;
        const int hd    = n & 63;
        const float bv = bias[n];
        if (which == 2) {
            #pragma unroll
            for (int mt = 0; mt < 4; ++mt) {
                const int m = m0 + wm + mt * 16 + g * 4;   // 4 consecutive toks
                const int bb = m >> 11, tok = m & 2047;
                const u32 p0 = cvtpk_bf16(acc[mt][nt][0] + bv, acc[mt][nt][1] + bv);
                const u32 p1 = cvtpk_bf16(acc[mt][nt][2] + bv, acc[mt][nt][3] + bv);
                u16* d = &vo[((size_t)(bb * NHEAD + head) * HD + hd) * SEQ + tok];
                *(u32*)&d[0] = p0;
                *(u32*)&d[2] = p1;
            }
        } else {
            u16* dst = (which == 0) ? qo : ko;
            const float scale = (which == 0) ? QSCALE : 1.0f;
            #pragma unroll
            for (int mt = 0; mt < 4; ++mt) {
                #pragma unroll
                for (int r = 0; r < 4; ++r) {
                    const int m = m0 + wm + mt * 16 + g * 4 + r;
                    const int bb = m >> 11, tok = m & 2047;
                    dst[((size_t)(bb * NHEAD + head) * SEQ + tok) * HD + hd] =
                        f2bf((acc[mt][nt][r] + bv) * scale);
                }
            }
        }
    }
}

// Projection GEMM: fp32 output + bias -> d_out.
__global__ __launch_bounds__(256) void gemm_proj(
    const u16* __restrict__ A, const u16* __restrict__ Bt,
    const float* __restrict__ bias, float* __restrict__ out)
{
    GEMM_MAINLOOP(A, Bt)
    #pragma unroll
    for (int nt = 0; nt < 4; ++nt) {
        const int n = n0 + wn + nt * 16 + li;
        const float bv = bias[n];
        #pragma unroll
        for (int mt = 0; mt < 4; ++mt) {
            #pragma unroll
            for (int r = 0; r < 4; ++r) {
                const int m = m0 + wm + mt * 16 + g * 4 + r;
                out[(size_t)m * DIM + n] = acc[mt][nt][r] + bv;
            }
        }
    }
}

// ===========================================================================
// MFMA flash attention R20: R19's 8-wave QBLK=256 kernel with ALL staging via
// global_load_lds (R10-proven: conflicts 0), now LAYOUT-CONSISTENT with the
// V^T [B,H,hd,SEQ] produced by gemm_qkv (R15's NaN was staging V^T-style from
// an untransposed buffer -- the algebra itself was verified correct).
//   K: source pre-permuted (kperm rows) + bank-XOR pre-swizzled; LDS linear.
//   V: linear rows of V^T, same XOR swizzle. Both read back with the same
//   involution (rule 21 both-sides).
// Zero-LDS P via kperm, fixed-m softmax, 2-slot dbuf + one __syncthreads per
// tile (compiler-correct vmcnt drain), setprio on MFMA clusters, XCD-chunked
// block swizzle (FETCH 24.6 MB measured). LDS 2x(8+8) = 32 KB.
// ===========================================================================
#define NKT  (SEQ / 64)
#define ATTN_STAGE(buf, ktile)                                                 \
    {                                                                          \
        gload_lds16(&kg[(size_t)(ktile) * (64 * HD) + (size_t)key * HD + sl],  \
                    &Ks[buf][(w * 8) * 64]);                                   \
        gload_lds16(&vg[(size_t)rho * SEQ + (ktile) * 64 + sl],                \
                    &Vs[buf][(w * 8) * 64]);                                   \
    }

__global__ __launch_bounds__(512) void attn_mfma(
    const u16* __restrict__ q, const u16* __restrict__ k,
    const u16* __restrict__ v, u16* __restrict__ ao)
{
    __shared__ __align__(16) u16 Ks[2][64 * 64];
    __shared__ __align__(16) u16 Vs[2][64 * 64];

    const int t = threadIdx.x;
    const int lane = t & 63, w = t >> 6;        // w = 0..7
    const int g = lane >> 4, li = lane & 15;

    // XCD-chunked swizzle (512 blocks): xcd = flat&7 owns 64 consecutive swz
    int flat = blockIdx.y * 8 + blockIdx.x;     // gridDim.x = 8
    flat = (flat & 7) * 64 + (flat >> 3);
    const int q0 = (flat & 7) * 256;
    const int bh = flat >> 3;
    const size_t base = (size_t)bh * SEQ * HD;
    const u16* kg = k + base;
    const u16* vg = v + (size_t)bh * HD * SEQ;   // V^T [hd][SEQ]

    // Q B-frags, both halves: q-col = li, d-slice = ks*32 + g*8
    bf16x8 qf[2][2];
    #pragma unroll
    for (int h = 0; h < 2; ++h) {
        const size_t qrow = base + (size_t)(q0 + w * 32 + h * 16 + li) * HD;
        qf[h][0] = *(const bf16x8*)&q[qrow + g * 8];
        qf[h][1] = *(const bf16x8*)&q[qrow + 32 + g * 8];
    }

    float lsum[2] = {0.f, 0.f};
    f32x4 oacc[2][4];
    #pragma unroll
    for (int h = 0; h < 2; ++h)
        #pragma unroll
        for (int nt = 0; nt < 4; ++nt) oacc[h][nt] = (f32x4){0.f, 0.f, 0.f, 0.f};

    // staging map: wave w stages LDS rows [w*8, w*8+8) of K (kperm'd) and V^T
    const int srow = lane >> 3;                // 0..7 within wave's chunk
    const int sslot = lane & 7;                // 16B slot within row
    const int rho = w * 8 + srow;              // LDS row (K: mfma row; V: hd)
    const int key = (rho & 32) | (((rho >> 2) & 3) << 3)
                  | (((rho >> 4) & 1) << 2) | (rho & 3);   // global key for rho
    const int sl = (sslot ^ (rho & 7)) << 3;   // pre-swizzled source chunk
    const int x8 = li & 7;

    ATTN_STAGE(0, 0)
    __syncthreads();

    int cur = 0;
    for (int kt = 0; kt < NKT; ++kt) {
        if (kt + 1 < NKT) { ATTN_STAGE(cur ^ 1, kt + 1) }
        const u16* Kc = Ks[cur];
        const u16* Vc = Vs[cur];

        // QK^T: s[h][nt][r] = S[key=kperm(16nt+4g+r)][q=li]
        f32x4 s[2][4];
        __builtin_amdgcn_s_setprio(1);
        #pragma unroll
        for (int nt = 0; nt < 4; ++nt) {
            const int rowb = (nt * 16 + li) << 6;
            const bf16x8 kf0 = *(const bf16x8*)&Kc[rowb + ((g ^ x8) << 3)];
            const bf16x8 kf1 = *(const bf16x8*)&Kc[rowb + (((g ^ 4) ^ x8) << 3)];
            #pragma unroll
            for (int h = 0; h < 2; ++h) {
                f32x4 c = (f32x4){0.f, 0.f, 0.f, 0.f};
                c = __builtin_amdgcn_mfma_f32_16x16x32_bf16(kf0, qf[h][0], c, 0, 0, 0);
                c = __builtin_amdgcn_mfma_f32_16x16x32_bf16(kf1, qf[h][1], c, 0, 0, 0);
                s[h][nt] = c;
            }
        }
        __builtin_amdgcn_s_setprio(0);

        // fixed-m softmax + in-register P pack (kperm makes pb = own regs)
        bf16x8 pb[2][2];
        #pragma unroll
        for (int h = 0; h < 2; ++h) {
            float rs = 0.f;
            #pragma unroll
            for (int nt = 0; nt < 4; ++nt)
                #pragma unroll
                for (int r = 0; r < 4; ++r) {
                    const float p = exp2_fast(s[h][nt][r]);
                    s[h][nt][r] = p;
                    rs += p;
                }
            lsum[h] += rs;
            #pragma unroll
            for (int ks = 0; ks < 2; ++ks) {
                union { u32 u[4]; bf16x8 v8; } uu;
                uu.u[0] = cvtpk_bf16(s[h][2 * ks][0],     s[h][2 * ks][1]);
                uu.u[1] = cvtpk_bf16(s[h][2 * ks][2],     s[h][2 * ks][3]);
                uu.u[2] = cvtpk_bf16(s[h][2 * ks + 1][0], s[h][2 * ks + 1][1]);
                uu.u[3] = cvtpk_bf16(s[h][2 * ks + 1][2], s[h][2 * ks + 1][3]);
                pb[h][ks] = uu.v8;
            }
        }

        // PV: O^T[hd][q] += V^T[hd][key] * P^T[key][q]
        __builtin_amdgcn_s_setprio(1);
        #pragma unroll
        for (int ks = 0; ks < 2; ++ks) {
            #pragma unroll
            for (int nt = 0; nt < 4; ++nt) {
                const bf16x8 vb = *(const bf16x8*)
                    &Vc[((nt * 16 + li) << 6) + (((g ^ (ks << 2)) ^ x8) << 3)];
                #pragma unroll
                for (int h = 0; h < 2; ++h)
                    oacc[h][nt] = __builtin_amdgcn_mfma_f32_16x16x32_bf16(
                        vb, pb[h][ks], oacc[h][nt], 0, 0, 0);
            }
        }
        __builtin_amdgcn_s_setprio(0);

        __syncthreads();   // drains gload_lds (vmcnt 0) + protects buffers
        cur ^= 1;
    }

    // epilogue: reduce l over g-groups (each lane owns q=li), normalize, store
    const int bb = bh >> 4, hh = bh & 15;
    #pragma unroll
    for (int h = 0; h < 2; ++h) {
        float lf = lsum[h];
        lf += __shfl_xor(lf, 16);
        lf += __shfl_xor(lf, 32);
        const float inv = 1.0f / lf;
        const int tok = q0 + w * 32 + h * 16 + li;
        u16* dst = &ao[(size_t)(bb * SEQ + tok) * DIM + hh * HD];
        #pragma unroll
        for (int nt = 0; nt < 4; ++nt) {
            const u32 p0 = cvtpk_bf16(oacc[h][nt][0] * inv, oacc[h][nt][1] * inv);
            const u32 p1 = cvtpk_bf16(oacc[h][nt][2] * inv, oacc[h][nt][3] * inv);
            *(u32*)&dst[nt * 16 + g * 4]     = p0;
            *(u32*)&dst[nt * 16 + g * 4 + 2] = p1;
        }
    }
}

extern "C" void kernel_launch(void* const* d_in, const int* in_sizes, int n_in,
                              void* d_out, int out_size, void* d_ws, size_t ws_size,
                              hipStream_t stream)
{
    const float* x      = (const float*)d_in[0];
    const float* w_qkv  = (const float*)d_in[1];
    const float* b_qkv  = (const float*)d_in[2];
    const float* w_proj = (const float*)d_in[3];
    const float* b_proj = (const float*)d_in[4];
    float* out = (float*)d_out;

    // bf16 workspace (~92 MB)
    u16* xb  = (u16*)d_ws;                         // 8192x1024
    u16* wqt = xb  + (size_t)MTOT * DIM;           // 3072x1024 (transposed)
    u16* wpt = wqt + (size_t)QKV_N * DIM;          // 1024x1024 (transposed)
    u16* qb  = wpt + (size_t)DIM * DIM;            // [B,H,N,hd]
    u16* kb  = qb  + (size_t)MTOT * DIM;
    u16* vb  = kb  + (size_t)MTOT * DIM;           // V^T [B,H,hd,SEQ]
    u16* aob = vb  + (size_t)MTOT * DIM;           // [B,N,D]

    prep<<<8192 + 768 + 256, 256, 0, stream>>>(x, xb, w_qkv, wqt, w_proj, wpt);
    gemm_qkv<<<dim3(QKV_N / 128, MTOT / 128), 256, 0, stream>>>(xb, wqt, b_qkv, qb, kb, vb);
    attn_mfma<<<dim3(SEQ / 256, BATCH * NHEAD), 512, 0, stream>>>(qb, kb, vb, aob);
    gemm_proj<<<dim3(DIM / 128, MTOT / 128), 256, 0, stream>>>(aob, wpt, b_proj, out);
}